// Round 1
// baseline (83.514 us; speedup 1.0000x reference)
//
#include <hip/hip_runtime.h>

// PriorEncoder forward: row-gather from 4 tables + exp(2x) on the "logvar" ones.
//   pm = Wm_pos[idx]            [B, K]   f32
//   pv = exp(2*Wv_pos[idx])     [B, K]   f32
//   hm = Wm_het[idx]            [B, 1]   f32
//   hv = exp(2*Wv_het[idx])     [B, 1]   f32
// Outputs concatenated flat in return order into d_out (f32).
// K = 128 (32 float4 per row). Memory-bound streaming gather.

#define K_DIM 128
#define K4 (K_DIM / 4)   // 32 float4 per row

__global__ void encoder_gather_kernel(const int* __restrict__ idx,
                                      const float4* __restrict__ Wm_pos,
                                      const float4* __restrict__ Wv_pos,
                                      const float* __restrict__ Wm_het,
                                      const float* __restrict__ Wv_het,
                                      float4* __restrict__ out_pm,
                                      float4* __restrict__ out_pv,
                                      float* __restrict__ out_hm,
                                      float* __restrict__ out_hv,
                                      int B) {
    const long long total_pos = (long long)B * K4;   // float4 work items for pos tables
    const long long total     = total_pos + B;       // + het scalars
    const long long stride    = (long long)gridDim.x * blockDim.x;

    for (long long i = (long long)blockIdx.x * blockDim.x + threadIdx.x;
         i < total; i += stride) {
        if (i < total_pos) {
            // 32 consecutive lanes share one b -> indices[b] broadcast; float4
            // gathers of a 512B row are fully coalesced within the 32-lane group.
            const int b  = (int)(i >> 5);    // i / 32
            const int k4 = (int)(i & 31);    // i % 32
            const int id = idx[b];
            const long long src = (long long)id * K4 + k4;

            const float4 m = Wm_pos[src];
            const float4 v = Wv_pos[src];

            out_pm[i] = m;

            float4 e;
            e.x = expf(2.0f * v.x);
            e.y = expf(2.0f * v.y);
            e.z = expf(2.0f * v.z);
            e.w = expf(2.0f * v.w);
            out_pv[i] = e;
        } else {
            const int b  = (int)(i - total_pos);
            const int id = idx[b];
            out_hm[b] = Wm_het[id];
            out_hv[b] = expf(2.0f * Wv_het[id]);
        }
    }
}

extern "C" void kernel_launch(void* const* d_in, const int* in_sizes, int n_in,
                              void* d_out, int out_size, void* d_ws, size_t ws_size,
                              hipStream_t stream) {
    const int*   idx    = (const int*)d_in[0];
    const float* Wm_pos = (const float*)d_in[1];
    const float* Wv_pos = (const float*)d_in[2];
    const float* Wm_het = (const float*)d_in[3];
    const float* Wv_het = (const float*)d_in[4];

    const int B = in_sizes[0];

    float* out = (float*)d_out;
    float4* out_pm = (float4*)out;                               // [B, K]
    float4* out_pv = (float4*)(out + (long long)B * K_DIM);      // [B, K]
    float*  out_hm = out + 2LL * B * K_DIM;                      // [B]
    float*  out_hv = out + 2LL * B * K_DIM + B;                  // [B]

    const long long total = (long long)B * K4 + B;
    const int block = 256;
    // Memory-bound: ~2048 blocks + grid-stride (Guideline 11).
    long long want = (total + block - 1) / block;
    int grid = (int)(want < 2048 ? want : 2048);

    encoder_gather_kernel<<<grid, block, 0, stream>>>(
        idx, (const float4*)Wm_pos, (const float4*)Wv_pos,
        Wm_het, Wv_het, out_pm, out_pv, out_hm, out_hv, B);
}

// Round 2
// 69.213 us; speedup vs baseline: 1.2066x; 1.2066x over previous
//
#include <hip/hip_runtime.h>

// PriorEncoder forward: row-gather from 4 tables + exp(2x) on the "logvar" ones.
//   pm = Wm_pos[idx]            [B, K]   f32
//   pv = exp(2*Wv_pos[idx])     [B, K]   f32
//   hm = Wm_het[idx]            [B, 1]   f32
//   hv = exp(2*Wv_het[idx])     [B, 1]   f32
// Outputs concatenated flat in return order into d_out (f32).
// K = 128 (32 float4 per row). Memory-bound streaming gather.
//
// Round-2 structure: one thread per float4 work item (no grid-stride loop) for
// max TLP on the random-gather latency; nontemporal stores so the 206 MB of
// write-once output doesn't evict gathered rows from L2/L3.

#define K_DIM 128
#define K4 (K_DIM / 4)   // 32 float4 per row

typedef float f32x4 __attribute__((ext_vector_type(4)));

__global__ void __launch_bounds__(256)
encoder_pos_kernel(const int* __restrict__ idx,
                   const f32x4* __restrict__ Wm_pos,
                   const f32x4* __restrict__ Wv_pos,
                   f32x4* __restrict__ out_pm,
                   f32x4* __restrict__ out_pv) {
    const int i  = blockIdx.x * 256 + threadIdx.x;   // < B*K4 (grid sized exactly)
    const int b  = i >> 5;    // i / K4
    const int k4 = i & 31;    // i % K4
    const int id = idx[b];    // broadcast across each 32-lane group (L1 hit)
    const int src = id * K4 + k4;

    const f32x4 m = Wm_pos[src];
    const f32x4 v = Wv_pos[src];

    __builtin_nontemporal_store(m, &out_pm[i]);

    f32x4 e;
    e.x = expf(2.0f * v.x);
    e.y = expf(2.0f * v.y);
    e.z = expf(2.0f * v.z);
    e.w = expf(2.0f * v.w);
    __builtin_nontemporal_store(e, &out_pv[i]);
}

__global__ void __launch_bounds__(256)
encoder_het_kernel(const int* __restrict__ idx,
                   const float* __restrict__ Wm_het,
                   const float* __restrict__ Wv_het,
                   float* __restrict__ out_hm,
                   float* __restrict__ out_hv,
                   int B) {
    const int b = blockIdx.x * 256 + threadIdx.x;
    if (b >= B) return;
    const int id = idx[b];
    __builtin_nontemporal_store(Wm_het[id], &out_hm[b]);
    __builtin_nontemporal_store(expf(2.0f * Wv_het[id]), &out_hv[b]);
}

extern "C" void kernel_launch(void* const* d_in, const int* in_sizes, int n_in,
                              void* d_out, int out_size, void* d_ws, size_t ws_size,
                              hipStream_t stream) {
    const int*   idx    = (const int*)d_in[0];
    const float* Wm_pos = (const float*)d_in[1];
    const float* Wv_pos = (const float*)d_in[2];
    const float* Wm_het = (const float*)d_in[3];
    const float* Wv_het = (const float*)d_in[4];

    const int B = in_sizes[0];

    float* out = (float*)d_out;
    f32x4* out_pm = (f32x4*)out;                               // [B, K]
    f32x4* out_pv = (f32x4*)(out + (long long)B * K_DIM);      // [B, K]
    float* out_hm = out + 2LL * B * K_DIM;                     // [B]
    float* out_hv = out + 2LL * B * K_DIM + B;                 // [B]

    const int total_pos = B * K4;                  // 6.4M threads, one float4 each
    const int grid_pos  = (total_pos + 255) / 256; // exact multiple for B=200k
    encoder_pos_kernel<<<grid_pos, 256, 0, stream>>>(
        idx, (const f32x4*)Wm_pos, (const f32x4*)Wv_pos, out_pm, out_pv);

    const int grid_het = (B + 255) / 256;
    encoder_het_kernel<<<grid_het, 256, 0, stream>>>(
        idx, Wm_het, Wv_het, out_hm, out_hv, B);
}

// Round 3
// 66.629 us; speedup vs baseline: 1.2534x; 1.0388x over previous
//
#include <hip/hip_runtime.h>

// PriorEncoder forward: row-gather from 4 tables + exp(2x) on the "logvar" ones.
//   pm = Wm_pos[idx]            [B, K]   f32
//   pv = exp(2*Wv_pos[idx])     [B, K]   f32
//   hm = Wm_het[idx]            [B, 1]   f32
//   hv = exp(2*Wv_het[idx])     [B, 1]   f32
// Outputs concatenated flat in return order into d_out (f32).
// K = 128 (32 float4 per row). Memory-bound streaming gather.
//
// Round-3: single fused dispatch. First GRID_HET blocks handle the [B,1] het
// tables (tiny, hides under the bulk); remaining blocks do one float4 work
// item each (max TLP for random-gather latency). Nontemporal stores keep the
// 206 MB write-once output from evicting gathered rows in L2/L3.

#define K_DIM 128
#define K4 (K_DIM / 4)   // 32 float4 per row

typedef float f32x4 __attribute__((ext_vector_type(4)));

__global__ void __launch_bounds__(256)
encoder_fused_kernel(const int* __restrict__ idx,
                     const f32x4* __restrict__ Wm_pos,
                     const f32x4* __restrict__ Wv_pos,
                     const float* __restrict__ Wm_het,
                     const float* __restrict__ Wv_het,
                     f32x4* __restrict__ out_pm,
                     f32x4* __restrict__ out_pv,
                     float* __restrict__ out_hm,
                     float* __restrict__ out_hv,
                     int B, int grid_het) {
    if ((int)blockIdx.x < grid_het) {
        // ---- het path: one thread per batch element, 4B gathers ----
        const int b = blockIdx.x * 256 + threadIdx.x;
        if (b >= B) return;
        const int id = idx[b];
        __builtin_nontemporal_store(Wm_het[id], &out_hm[b]);
        __builtin_nontemporal_store(expf(2.0f * Wv_het[id]), &out_hv[b]);
    } else {
        // ---- pos path: one thread per float4; 32 lanes share one index ----
        const int i  = (blockIdx.x - grid_het) * 256 + threadIdx.x;  // < B*K4 exactly
        const int b  = i >> 5;    // i / K4
        const int k4 = i & 31;    // i % K4
        const int id = idx[b];    // broadcast within each 32-lane group
        const int src = id * K4 + k4;

        const f32x4 m = Wm_pos[src];
        const f32x4 v = Wv_pos[src];

        __builtin_nontemporal_store(m, &out_pm[i]);

        f32x4 e;
        e.x = expf(2.0f * v.x);
        e.y = expf(2.0f * v.y);
        e.z = expf(2.0f * v.z);
        e.w = expf(2.0f * v.w);
        __builtin_nontemporal_store(e, &out_pv[i]);
    }
}

extern "C" void kernel_launch(void* const* d_in, const int* in_sizes, int n_in,
                              void* d_out, int out_size, void* d_ws, size_t ws_size,
                              hipStream_t stream) {
    const int*   idx    = (const int*)d_in[0];
    const float* Wm_pos = (const float*)d_in[1];
    const float* Wv_pos = (const float*)d_in[2];
    const float* Wm_het = (const float*)d_in[3];
    const float* Wv_het = (const float*)d_in[4];

    const int B = in_sizes[0];

    float* out = (float*)d_out;
    f32x4* out_pm = (f32x4*)out;                               // [B, K]
    f32x4* out_pv = (f32x4*)(out + (long long)B * K_DIM);      // [B, K]
    float* out_hm = out + 2LL * B * K_DIM;                     // [B]
    float* out_hv = out + 2LL * B * K_DIM + B;                 // [B]

    const int grid_het = (B + 255) / 256;          // 782 blocks lead
    const int grid_pos = (B * K4 + 255) / 256;     // 25000 blocks (exact for B=200k)

    encoder_fused_kernel<<<grid_het + grid_pos, 256, 0, stream>>>(
        idx, (const f32x4*)Wm_pos, (const f32x4*)Wv_pos, Wm_het, Wv_het,
        out_pm, out_pv, out_hm, out_hv, B, grid_het);
}